// Round 3
// baseline (1003.279 us; speedup 1.0000x reference)
//
#include <hip/hip_runtime.h>

#define B_    64
#define S_    1024
#define CIN   5
#define K_    4
#define H1    64
#define H2    16
#define OUT_  32
#define L1_   1021      // S - K + 1
#define C1    22        // H2 + CIN + 1
#define SIGC1 506       // C1 + C1*C1
#define L2_   1018      // L1 - K + 1
#define SIGC2 272       // H2 + H2*H2

// ---------------- Kernel A: augment1 (conv k=4 -> relu -> 1x1 -> relu -> 1x1), concat [orig, time, conv] ----------
__global__ __launch_bounds__(256) void aug1_kernel(
    const float* __restrict__ x,
    const float* __restrict__ w0, const float* __restrict__ b0,
    const float* __restrict__ w1, const float* __restrict__ b1,
    const float* __restrict__ w2, const float* __restrict__ b2,
    float* __restrict__ h) {
  int b = blockIdx.y;
  int l = blockIdx.x * 256 + threadIdx.x;
  if (l >= L1_) return;
  const float* xb = x + (size_t)b * S_ * CIN;

  float t1[H1];
#pragma unroll
  for (int o = 0; o < H1; ++o) t1[o] = b0[o];
  for (int j = 0; j < K_; ++j) {
    for (int c = 0; c < CIN; ++c) {
      float xv = xb[(l + j) * CIN + c];
#pragma unroll
      for (int o = 0; o < H1; ++o) t1[o] += xv * w0[o * (CIN * K_) + c * K_ + j];
    }
  }
#pragma unroll
  for (int o = 0; o < H1; ++o) t1[o] = fmaxf(t1[o], 0.f);

  float t3[H2];
#pragma unroll
  for (int q = 0; q < H2; ++q) t3[q] = b2[q];
  for (int ch = 0; ch < 4; ++ch) {
    float t2c[16];
    for (int oc = 0; oc < 16; ++oc) {
      int o = ch * 16 + oc;
      float a = b1[o];
#pragma unroll
      for (int i = 0; i < H1; ++i) a += t1[i] * w1[o * H1 + i];
      t2c[oc] = fmaxf(a, 0.f);
    }
#pragma unroll
    for (int q = 0; q < H2; ++q) {
      float a = t3[q];
#pragma unroll
      for (int oc = 0; oc < 16; ++oc) a += t2c[oc] * w2[q * H1 + ch * 16 + oc];
      t3[q] = a;
    }
  }

  float* hr = h + ((size_t)b * L1_ + l) * C1;
#pragma unroll
  for (int c = 0; c < CIN; ++c) hr[c] = xb[(l + K_ - 1) * CIN + c];
  hr[CIN] = (float)l / (float)(L1_ - 1);
#pragma unroll
  for (int q = 0; q < H2; ++q) hr[CIN + 1 + q] = t3[q];
}

// ---------------- Kernel B: streaming signature depth 2 over h -> s1 (B, L1, 506) -----------------
// S1[t] = h[t] (prefix sum of increments with zero basepoint). S2 update:
// S2 += prev_i * dx_j + 0.5*dx_i*dx_j, dx = cur - prev.
__global__ __launch_bounds__(512) void sig1_kernel(const float* __restrict__ h, float* __restrict__ s1) {
  int b = blockIdx.x;
  int tid = threadIdx.x;
  __shared__ float curb[2][C1];
  if (tid < C1) curb[1][tid] = 0.f;
  int i = tid / C1, j = tid - i * C1;  // valid for tid < 484
  float s2 = 0.f;
  int par = 0;
  const float* hb = h + (size_t)b * L1_ * C1;
  float* s1b = s1 + (size_t)b * L1_ * SIGC1;
  __syncthreads();
  for (int t = 0; t < L1_; ++t) {
    if (tid < C1) curb[par][tid] = hb[t * C1 + tid];
    __syncthreads();
    float* outr = s1b + (size_t)t * SIGC1;
    if (tid < C1 * C1) {
      float cj = curb[par][j], pj = curb[par ^ 1][j];
      float ci = curb[par][i], pi = curb[par ^ 1][i];
      float dj = cj - pj;
      s2 += pi * dj + 0.5f * (ci - pi) * dj;
      outr[C1 + tid] = s2;
    } else if (tid < C1 * C1 + C1) {
      int c = tid - C1 * C1;
      outr[c] = curb[par][c];
    }
    __syncthreads();
    par ^= 1;
  }
}

// ---------------- Kernel W: transpose a2_w0 (O,C,K) -> w0t[(c*4+j)*64 + o] --------------------
__global__ void wt_kernel(const float* __restrict__ w0, float* __restrict__ w0t) {
  int idx = blockIdx.x * 256 + threadIdx.x;
  if (idx >= SIGC1 * K_ * H1) return;
  int o = idx & 63;
  int cj = idx >> 6;
  w0t[idx] = w0[o * (SIGC1 * K_) + cj];
}

// ---------------- Kernel C: big conv (506ch, k=4 -> 64ch) as tiled GEMM ----------------------
// t1[b,l,o] = b0[o] + sum_{c,j} s1[b,l+j,c] * w0t[(c*4+j)*64+o]
#define CCHUNK 22
__global__ __launch_bounds__(256) void conv2_kernel(
    const float* __restrict__ s1, const float* __restrict__ w0t,
    const float* __restrict__ b0, float* __restrict__ t1) {
  __shared__ float As[CCHUNK][68];        // [c][row 0..66]
  __shared__ float Bs[CCHUNK * 4][64];    // [k=(c,j)][o]
  int b = blockIdx.y;
  int l0 = blockIdx.x * 64;
  int tid = threadIdx.x;
  int to = (tid & 15) * 4;
  int tl = (tid >> 4) * 4;
  float acc[4][4] = {};
  const float* s1b = s1 + (size_t)b * L1_ * SIGC1;

  for (int cc0 = 0; cc0 < SIGC1; cc0 += CCHUNK) {
    __syncthreads();
    // stage A: 67 rows x CCHUNK cols (transposed into As[c][i])
    for (int idx = tid; idx < 67 * CCHUNK; idx += 256) {
      int i = idx / CCHUNK;
      int c = idx - i * CCHUNK;
      int row = l0 + i;
      if (row > L1_ - 1) row = L1_ - 1;
      As[c][i] = s1b[(size_t)row * SIGC1 + cc0 + c];
    }
    // stage B: contiguous copy
    const float4* wsrc = (const float4*)(w0t + cc0 * 4 * 64);
    for (int idx = tid; idx < CCHUNK * 4 * 64 / 4; idx += 256) {
      ((float4*)Bs)[idx] = wsrc[idx];
    }
    __syncthreads();
#pragma unroll 2
    for (int c = 0; c < CCHUNK; ++c) {
      float av[8];
      *(float4*)&av[0] = *(float4*)&As[c][tl];
      *(float4*)&av[4] = *(float4*)&As[c][tl + 4];
#pragma unroll
      for (int j = 0; j < 4; ++j) {
        float4 bv = *(float4*)&Bs[c * 4 + j][to];
#pragma unroll
        for (int r = 0; r < 4; ++r) {
          acc[r][0] += av[r + j] * bv.x;
          acc[r][1] += av[r + j] * bv.y;
          acc[r][2] += av[r + j] * bv.z;
          acc[r][3] += av[r + j] * bv.w;
        }
      }
    }
  }
  float bb0 = b0[to], bb1 = b0[to + 1], bb2 = b0[to + 2], bb3 = b0[to + 3];
#pragma unroll
  for (int r = 0; r < 4; ++r) {
    int l = l0 + tl + r;
    if (l < L2_) {
      float4 o4;
      o4.x = acc[r][0] + bb0;
      o4.y = acc[r][1] + bb1;
      o4.z = acc[r][2] + bb2;
      o4.w = acc[r][3] + bb3;
      *(float4*)&t1[((size_t)b * L2_ + l) * 64 + to] = o4;
    }
  }
}

// ---------------- Kernel D: relu -> 1x1 (64->64) -> relu -> 1x1 (64->16) --------------------
__global__ __launch_bounds__(256) void pw2_kernel(
    const float* __restrict__ t1,
    const float* __restrict__ w1, const float* __restrict__ b1,
    const float* __restrict__ w2, const float* __restrict__ b2,
    float* __restrict__ h2) {
  int b = blockIdx.y;
  int l = blockIdx.x * 256 + threadIdx.x;
  if (l >= L2_) return;
  const float* row = t1 + ((size_t)b * L2_ + l) * 64;
  float v[64];
#pragma unroll
  for (int i = 0; i < 64; i += 4) {
    float4 r4 = *(const float4*)&row[i];
    v[i] = fmaxf(r4.x, 0.f);
    v[i + 1] = fmaxf(r4.y, 0.f);
    v[i + 2] = fmaxf(r4.z, 0.f);
    v[i + 3] = fmaxf(r4.w, 0.f);
  }
  float acc3[16];
#pragma unroll
  for (int q = 0; q < 16; ++q) acc3[q] = b2[q];
  for (int ch = 0; ch < 4; ++ch) {
    float t2c[16];
    for (int oc = 0; oc < 16; ++oc) {
      int o = ch * 16 + oc;
      float a = b1[o];
#pragma unroll
      for (int i = 0; i < 64; ++i) a += v[i] * w1[o * 64 + i];
      t2c[oc] = fmaxf(a, 0.f);
    }
#pragma unroll
    for (int q = 0; q < 16; ++q) {
      float a = acc3[q];
#pragma unroll
      for (int oc = 0; oc < 16; ++oc) a += t2c[oc] * w2[q * 64 + ch * 16 + oc];
      acc3[q] = a;
    }
  }
  float* out = h2 + ((size_t)b * L2_ + l) * H2;
#pragma unroll
  for (int q = 0; q < H2; ++q) out[q] = acc3[q];
}

// ---------------- Kernel E: become_constant + signature2 (non-stream) + linear --------------
__global__ __launch_bounds__(256) void sig2lin_kernel(
    const float* __restrict__ h2, const int* __restrict__ lengths,
    const float* __restrict__ lin_w, const float* __restrict__ lin_b,
    float* __restrict__ out) {
  int b = blockIdx.x;
  int tid = threadIdx.x;
  int i = tid >> 4, j = tid & 15;
  __shared__ float curb[2][H2];
  __shared__ float s2s[SIGC2];
  if (tid < H2) curb[1][tid] = 0.f;
  float s2 = 0.f;
  int par = 0;
  int adjm1 = lengths[b] - (2 * K_ - 2) - 1;  // lengths - 7
  const float* h2b = h2 + (size_t)b * L2_ * H2;
  __syncthreads();
  for (int t = 0; t < L2_; ++t) {
    int row = t < adjm1 ? t : adjm1;
    if (tid < H2) curb[par][tid] = h2b[row * H2 + tid];
    __syncthreads();
    {
      float cj = curb[par][j], pj = curb[par ^ 1][j];
      float ci = curb[par][i], pi = curb[par ^ 1][i];
      float dj = cj - pj;
      s2 += pi * dj + 0.5f * (ci - pi) * dj;
    }
    __syncthreads();
    par ^= 1;
  }
  // final S1 = h2c[L2-1] is in curb[par^1]
  if (tid < H2) s2s[tid] = curb[par ^ 1][tid];
  s2s[H2 + tid] = s2;
  __syncthreads();
  if (tid < OUT_) {
    float a = lin_b[tid];
    for (int c = 0; c < SIGC2; ++c) a += s2s[c] * lin_w[tid * SIGC2 + c];
    out[b * OUT_ + tid] = a;
  }
}

extern "C" void kernel_launch(void* const* d_in, const int* in_sizes, int n_in,
                              void* d_out, int out_size, void* d_ws, size_t ws_size,
                              hipStream_t stream) {
  const float* x      = (const float*)d_in[0];
  const int*   lengths= (const int*)d_in[1];
  const float* a1_w0  = (const float*)d_in[2];
  const float* a1_b0  = (const float*)d_in[3];
  const float* a1_w1  = (const float*)d_in[4];
  const float* a1_b1  = (const float*)d_in[5];
  const float* a1_w2  = (const float*)d_in[6];
  const float* a1_b2  = (const float*)d_in[7];
  const float* a2_w0  = (const float*)d_in[8];
  const float* a2_b0  = (const float*)d_in[9];
  const float* a2_w1  = (const float*)d_in[10];
  const float* a2_b1  = (const float*)d_in[11];
  const float* a2_w2  = (const float*)d_in[12];
  const float* a2_b2  = (const float*)d_in[13];
  const float* lin_w  = (const float*)d_in[14];
  const float* lin_b  = (const float*)d_in[15];
  float* outp = (float*)d_out;

  float* ws = (float*)d_ws;
  size_t off = 0;
  float* h   = ws + off; off += (size_t)B_ * L1_ * C1;      // 1,437,568
  float* s1  = ws + off; off += (size_t)B_ * L1_ * SIGC1;   // 33,064,064
  float* w0t = ws + off; off += (size_t)SIGC1 * K_ * H1;    // 129,536
  float* t1  = ws + off; off += (size_t)B_ * L2_ * 64;      // 4,169,728
  float* h2  = ws + off; off += (size_t)B_ * L2_ * H2;      // 1,042,432

  aug1_kernel<<<dim3(4, B_), 256, 0, stream>>>(x, a1_w0, a1_b0, a1_w1, a1_b1, a1_w2, a1_b2, h);
  wt_kernel<<<(SIGC1 * K_ * H1 + 255) / 256, 256, 0, stream>>>(a2_w0, w0t);
  sig1_kernel<<<B_, 512, 0, stream>>>(h, s1);
  conv2_kernel<<<dim3(16, B_), 256, 0, stream>>>(s1, w0t, a2_b0, t1);
  pw2_kernel<<<dim3(4, B_), 256, 0, stream>>>(t1, a2_w1, a2_b1, a2_w2, a2_b2, h2);
  sig2lin_kernel<<<B_, 256, 0, stream>>>(h2, lengths, lin_w, lin_b, outp);
}

// Round 4
// 495.312 us; speedup vs baseline: 2.0256x; 2.0256x over previous
//
#include <hip/hip_runtime.h>

#define B_    64
#define S_    1024
#define CIN   5
#define K_    4
#define H1    64
#define H2    16
#define OUT_  32
#define L1_   1021      // S - K + 1
#define C1    22        // H2 + CIN + 1
#define C1SQ  484
#define SIGC1 506       // C1 + C1*C1
#define L2_   1018      // L1 - K + 1
#define SIGC2 272       // H2 + H2*H2
#define NCH   16        // time chunks (64 steps each)

// ---------------- Kernel A: augment1 (conv k=4 -> relu -> 1x1 -> relu -> 1x1), concat [orig, time, conv] ----------
__global__ __launch_bounds__(256) void aug1_kernel(
    const float* __restrict__ x,
    const float* __restrict__ w0, const float* __restrict__ b0,
    const float* __restrict__ w1, const float* __restrict__ b1,
    const float* __restrict__ w2, const float* __restrict__ b2,
    float* __restrict__ h) {
  int b = blockIdx.y;
  int l = blockIdx.x * 256 + threadIdx.x;
  if (l >= L1_) return;
  const float* xb = x + (size_t)b * S_ * CIN;

  float t1[H1];
#pragma unroll
  for (int o = 0; o < H1; ++o) t1[o] = b0[o];
  for (int j = 0; j < K_; ++j) {
    for (int c = 0; c < CIN; ++c) {
      float xv = xb[(l + j) * CIN + c];
#pragma unroll
      for (int o = 0; o < H1; ++o) t1[o] += xv * w0[o * (CIN * K_) + c * K_ + j];
    }
  }
#pragma unroll
  for (int o = 0; o < H1; ++o) t1[o] = fmaxf(t1[o], 0.f);

  float t3[H2];
#pragma unroll
  for (int q = 0; q < H2; ++q) t3[q] = b2[q];
  for (int ch = 0; ch < 4; ++ch) {
    float t2c[16];
    for (int oc = 0; oc < 16; ++oc) {
      int o = ch * 16 + oc;
      float a = b1[o];
#pragma unroll
      for (int i = 0; i < H1; ++i) a += t1[i] * w1[o * H1 + i];
      t2c[oc] = fmaxf(a, 0.f);
    }
#pragma unroll
    for (int q = 0; q < H2; ++q) {
      float a = t3[q];
#pragma unroll
      for (int oc = 0; oc < 16; ++oc) a += t2c[oc] * w2[q * H1 + ch * 16 + oc];
      t3[q] = a;
    }
  }

  float* hr = h + ((size_t)b * L1_ + l) * C1;
#pragma unroll
  for (int c = 0; c < CIN; ++c) hr[c] = xb[(l + K_ - 1) * CIN + c];
  hr[CIN] = (float)l / (float)(L1_ - 1);
#pragma unroll
  for (int q = 0; q < H2; ++q) hr[CIN + 1 + q] = t3[q];
}

// ---------------- sig1 phase A: per-(b,chunk) local depth-2 scan, chunk totals only -----------------
// Shifted coords: P[t] = h[t] - h_pre (h_pre = h[chunk_start-1], 0 for chunk 0).
__global__ __launch_bounds__(512) void sig1a_kernel(const float* __restrict__ h, float* __restrict__ s2tot) {
  int k = blockIdx.x, b = blockIdx.y;
  int tid = threadIdx.x;
  int start = k * 64, end = min(start + 63, L1_ - 1);
  const float* hb = h + (size_t)b * L1_ * C1;
  __shared__ float curb[2][C1];
  __shared__ float hpre[C1];
  if (tid < C1) {
    float v = (k == 0) ? 0.f : hb[(start - 1) * C1 + tid];
    hpre[tid] = v;
    curb[1][tid] = 0.f;  // shifted prev
  }
  int i = tid / C1, j = tid - i * C1;
  float s2 = 0.f;
  int par = 0;
  __syncthreads();
  for (int t = start; t <= end; ++t) {
    if (tid < C1) curb[par][tid] = hb[t * C1 + tid] - hpre[tid];
    __syncthreads();
    if (tid < C1SQ) {
      float cj = curb[par][j], pj = curb[par ^ 1][j];
      float ci = curb[par][i], pi = curb[par ^ 1][i];
      float dj = cj - pj;
      s2 += pi * dj + 0.5f * (ci - pi) * dj;
    }
    __syncthreads();
    par ^= 1;
  }
  if (tid < C1SQ) s2tot[((size_t)b * NCH + k) * C1SQ + tid] = s2;
}

// ---------------- sig1 phase B: 16-step exclusive prefix combine via Chen -----------------
__global__ __launch_bounds__(512) void sig1b_kernel(const float* __restrict__ h, const float* __restrict__ s2tot,
                                                    float* __restrict__ s2pre) {
  int b = blockIdx.x;
  int tid = threadIdx.x;
  const float* hb = h + (size_t)b * L1_ * C1;
  __shared__ float bv[NCH + 1][C1];  // bv[k]=h[64k-1] (0 for k=0), bv[16]=h[1020]
  if (tid < (NCH + 1) * C1) {
    int kk = tid / C1, c = tid - kk * C1;
    float v = 0.f;
    if (kk > 0) {
      int row = (kk == NCH) ? (L1_ - 1) : (64 * kk - 1);
      v = hb[row * C1 + c];
    }
    bv[kk][c] = v;
  }
  int i = tid / C1, j = tid - i * C1;
  __syncthreads();
  if (tid >= C1SQ) return;
  float s2p = 0.f;
  for (int k = 0; k < NCH; ++k) {
    size_t idx = ((size_t)b * NCH + k) * C1SQ + tid;
    s2pre[idx] = s2p;
    s2p += bv[k][i] * (bv[k + 1][j] - bv[k][j]) + s2tot[idx];
  }
}

// ---------------- sig1 phase C: re-scan chunks, emit corrected global stream signature -----------------
__global__ __launch_bounds__(512) void sig1c_kernel(const float* __restrict__ h, const float* __restrict__ s2pre,
                                                    float* __restrict__ s1) {
  int k = blockIdx.x, b = blockIdx.y;
  int tid = threadIdx.x;
  int start = k * 64, end = min(start + 63, L1_ - 1);
  const float* hb = h + (size_t)b * L1_ * C1;
  float* s1b = s1 + (size_t)b * L1_ * SIGC1;
  __shared__ float curb[2][C1];
  __shared__ float hpre[C1];
  if (tid < C1) {
    float v = (k == 0) ? 0.f : hb[(start - 1) * C1 + tid];
    hpre[tid] = v;
    curb[1][tid] = 0.f;
  }
  int i = tid / C1, j = tid - i * C1;
  float s2 = 0.f;
  int par = 0;
  __syncthreads();
  float s2p = 0.f, hpi = 0.f;
  if (tid < C1SQ) {
    s2p = s2pre[((size_t)b * NCH + k) * C1SQ + tid];
    hpi = hpre[i];
  }
  for (int t = start; t <= end; ++t) {
    if (tid < C1) curb[par][tid] = hb[t * C1 + tid] - hpre[tid];
    __syncthreads();
    float* outr = s1b + (size_t)t * SIGC1;
    if (tid < C1SQ) {
      float cj = curb[par][j], pj = curb[par ^ 1][j];
      float ci = curb[par][i], pi = curb[par ^ 1][i];
      float dj = cj - pj;
      s2 += pi * dj + 0.5f * (ci - pi) * dj;
      outr[C1 + tid] = s2p + hpi * cj + s2;      // Chen correction: A2 + A1 (x) B1 + B2
    } else if (tid < C1SQ + C1) {
      int c = tid - C1SQ;
      outr[c] = curb[par][c] + hpre[c];          // level 1 = unshifted h[t]
    }
    __syncthreads();
    par ^= 1;
  }
}

// ---------------- Kernel W: transpose a2_w0 (O,C,K) -> w0t[(c*4+j)*64 + o] --------------------
__global__ void wt_kernel(const float* __restrict__ w0, float* __restrict__ w0t) {
  int idx = blockIdx.x * 256 + threadIdx.x;
  if (idx >= SIGC1 * K_ * H1) return;
  int o = idx & 63;
  int cj = idx >> 6;
  w0t[idx] = w0[o * (SIGC1 * K_) + cj];
}

// ---------------- Kernel C: big conv (506ch, k=4 -> 64ch) as tiled GEMM ----------------------
#define CCHUNK 22
__global__ __launch_bounds__(256) void conv2_kernel(
    const float* __restrict__ s1, const float* __restrict__ w0t,
    const float* __restrict__ b0, float* __restrict__ t1) {
  __shared__ float As[CCHUNK][68];        // [c][row 0..66]
  __shared__ float Bs[CCHUNK * 4][64];    // [k=(c,j)][o]
  int b = blockIdx.y;
  int l0 = blockIdx.x * 64;
  int tid = threadIdx.x;
  int to = (tid & 15) * 4;
  int tl = (tid >> 4) * 4;
  float acc[4][4] = {};
  const float* s1b = s1 + (size_t)b * L1_ * SIGC1;

  for (int cc0 = 0; cc0 < SIGC1; cc0 += CCHUNK) {
    __syncthreads();
    for (int idx = tid; idx < 67 * CCHUNK; idx += 256) {
      int i = idx / CCHUNK;
      int c = idx - i * CCHUNK;
      int row = l0 + i;
      if (row > L1_ - 1) row = L1_ - 1;
      As[c][i] = s1b[(size_t)row * SIGC1 + cc0 + c];
    }
    const float4* wsrc = (const float4*)(w0t + cc0 * 4 * 64);
    for (int idx = tid; idx < CCHUNK * 4 * 64 / 4; idx += 256) {
      ((float4*)Bs)[idx] = wsrc[idx];
    }
    __syncthreads();
#pragma unroll 2
    for (int c = 0; c < CCHUNK; ++c) {
      float av[8];
      *(float4*)&av[0] = *(float4*)&As[c][tl];
      *(float4*)&av[4] = *(float4*)&As[c][tl + 4];
#pragma unroll
      for (int j = 0; j < 4; ++j) {
        float4 bv = *(float4*)&Bs[c * 4 + j][to];
#pragma unroll
        for (int r = 0; r < 4; ++r) {
          acc[r][0] += av[r + j] * bv.x;
          acc[r][1] += av[r + j] * bv.y;
          acc[r][2] += av[r + j] * bv.z;
          acc[r][3] += av[r + j] * bv.w;
        }
      }
    }
  }
  float bb0 = b0[to], bb1 = b0[to + 1], bb2 = b0[to + 2], bb3 = b0[to + 3];
#pragma unroll
  for (int r = 0; r < 4; ++r) {
    int l = l0 + tl + r;
    if (l < L2_) {
      float4 o4;
      o4.x = acc[r][0] + bb0;
      o4.y = acc[r][1] + bb1;
      o4.z = acc[r][2] + bb2;
      o4.w = acc[r][3] + bb3;
      *(float4*)&t1[((size_t)b * L2_ + l) * 64 + to] = o4;
    }
  }
}

// ---------------- Kernel D: relu -> 1x1 (64->64) -> relu -> 1x1 (64->16) --------------------
__global__ __launch_bounds__(256) void pw2_kernel(
    const float* __restrict__ t1,
    const float* __restrict__ w1, const float* __restrict__ b1,
    const float* __restrict__ w2, const float* __restrict__ b2,
    float* __restrict__ h2) {
  int b = blockIdx.y;
  int l = blockIdx.x * 256 + threadIdx.x;
  if (l >= L2_) return;
  const float* row = t1 + ((size_t)b * L2_ + l) * 64;
  float v[64];
#pragma unroll
  for (int i = 0; i < 64; i += 4) {
    float4 r4 = *(const float4*)&row[i];
    v[i] = fmaxf(r4.x, 0.f);
    v[i + 1] = fmaxf(r4.y, 0.f);
    v[i + 2] = fmaxf(r4.z, 0.f);
    v[i + 3] = fmaxf(r4.w, 0.f);
  }
  float acc3[16];
#pragma unroll
  for (int q = 0; q < 16; ++q) acc3[q] = b2[q];
  for (int ch = 0; ch < 4; ++ch) {
    float t2c[16];
    for (int oc = 0; oc < 16; ++oc) {
      int o = ch * 16 + oc;
      float a = b1[o];
#pragma unroll
      for (int i = 0; i < 64; ++i) a += v[i] * w1[o * 64 + i];
      t2c[oc] = fmaxf(a, 0.f);
    }
#pragma unroll
    for (int q = 0; q < 16; ++q) {
      float a = acc3[q];
#pragma unroll
      for (int oc = 0; oc < 16; ++oc) a += t2c[oc] * w2[q * 64 + ch * 16 + oc];
      acc3[q] = a;
    }
  }
  float* out = h2 + ((size_t)b * L2_ + l) * H2;
#pragma unroll
  for (int q = 0; q < H2; ++q) out[q] = acc3[q];
}

// ---------------- sig2 phase A: per-(b,chunk) local scan with become_constant clamp -----------------
__global__ __launch_bounds__(256) void sig2a_kernel(const float* __restrict__ h2, const int* __restrict__ lengths,
                                                    float* __restrict__ s2tot2) {
  int k = blockIdx.x, b = blockIdx.y;
  int tid = threadIdx.x;
  int i = tid >> 4, j = tid & 15;
  int adjm1 = lengths[b] - (2 * K_ - 2) - 1;  // lengths - 7
  int start = k * 64, end = min(start + 63, L2_ - 1);
  size_t oidx = ((size_t)b * NCH + k) * 256 + tid;
  if (k > 0 && start - 1 >= adjm1) {  // whole chunk in the constant tail -> zero increments
    s2tot2[oidx] = 0.f;
    return;
  }
  const float* h2b = h2 + (size_t)b * L2_ * H2;
  __shared__ float curb[2][H2];
  __shared__ float pre[H2];
  if (tid < H2) {
    float v = 0.f;
    if (k > 0) {
      int row = min(start - 1, adjm1);
      v = h2b[row * H2 + tid];
    }
    pre[tid] = v;
    curb[1][tid] = 0.f;
  }
  float s2 = 0.f;
  int par = 0;
  __syncthreads();
  for (int t = start; t <= end; ++t) {
    int row = min(t, adjm1);
    if (tid < H2) curb[par][tid] = h2b[row * H2 + tid] - pre[tid];
    __syncthreads();
    {
      float cj = curb[par][j], pj = curb[par ^ 1][j];
      float ci = curb[par][i], pi = curb[par ^ 1][i];
      float dj = cj - pj;
      s2 += pi * dj + 0.5f * (ci - pi) * dj;
    }
    __syncthreads();
    par ^= 1;
  }
  s2tot2[oidx] = s2;
}

// ---------------- sig2 phase B: 16-step Chen combine + final linear -----------------
__global__ __launch_bounds__(256) void sig2b_kernel(const float* __restrict__ h2, const int* __restrict__ lengths,
                                                    const float* __restrict__ s2tot2,
                                                    const float* __restrict__ lin_w, const float* __restrict__ lin_b,
                                                    float* __restrict__ out) {
  int b = blockIdx.x;
  int tid = threadIdx.x;
  int i = tid >> 4, j = tid & 15;
  int adjm1 = lengths[b] - (2 * K_ - 2) - 1;
  const float* h2b = h2 + (size_t)b * L2_ * H2;
  __shared__ float bv[NCH + 1][H2];  // boundary values of clamped path
  __shared__ float s2s[SIGC2];
  for (int idx = tid; idx < (NCH + 1) * H2; idx += 256) {
    int kk = idx >> 4, c = idx & 15;
    float v = 0.f;
    if (kk > 0) {
      int row = min(64 * kk - 1, adjm1);
      v = h2b[row * H2 + c];
    }
    bv[kk][c] = v;
  }
  __syncthreads();
  float s2 = 0.f;
  for (int k = 0; k < NCH; ++k) {
    s2 += bv[k][i] * (bv[k + 1][j] - bv[k][j]) + s2tot2[((size_t)b * NCH + k) * 256 + tid];
  }
  s2s[H2 + tid] = s2;
  if (tid < H2) s2s[tid] = bv[NCH][tid];  // final level-1 = clamped h2 endpoint
  __syncthreads();
  if (tid < OUT_) {
    float a = lin_b[tid];
    for (int c = 0; c < SIGC2; ++c) a += s2s[c] * lin_w[tid * SIGC2 + c];
    out[b * OUT_ + tid] = a;
  }
}

extern "C" void kernel_launch(void* const* d_in, const int* in_sizes, int n_in,
                              void* d_out, int out_size, void* d_ws, size_t ws_size,
                              hipStream_t stream) {
  const float* x      = (const float*)d_in[0];
  const int*   lengths= (const int*)d_in[1];
  const float* a1_w0  = (const float*)d_in[2];
  const float* a1_b0  = (const float*)d_in[3];
  const float* a1_w1  = (const float*)d_in[4];
  const float* a1_b1  = (const float*)d_in[5];
  const float* a1_w2  = (const float*)d_in[6];
  const float* a1_b2  = (const float*)d_in[7];
  const float* a2_w0  = (const float*)d_in[8];
  const float* a2_b0  = (const float*)d_in[9];
  const float* a2_w1  = (const float*)d_in[10];
  const float* a2_b1  = (const float*)d_in[11];
  const float* a2_w2  = (const float*)d_in[12];
  const float* a2_b2  = (const float*)d_in[13];
  const float* lin_w  = (const float*)d_in[14];
  const float* lin_b  = (const float*)d_in[15];
  float* outp = (float*)d_out;

  float* ws = (float*)d_ws;
  size_t off = 0;
  float* h   = ws + off; off += (size_t)B_ * L1_ * C1;      // 1,437,568
  float* s1  = ws + off; off += (size_t)B_ * L1_ * SIGC1;   // 33,064,064
  float* w0t = ws + off; off += (size_t)SIGC1 * K_ * H1;    // 129,536
  float* t1  = ws + off; off += (size_t)B_ * L2_ * 64;      // 4,169,728
  float* h2  = ws + off; off += (size_t)B_ * L2_ * H2;      // 1,042,432
  // Aliases into the t1 region (dead before conv2 / after pw2):
  float* s2tot1 = t1;                                       // 495,616 (sig1a -> sig1b)
  float* s2pre1 = t1 + (size_t)B_ * NCH * C1SQ;             // 495,616 (sig1b -> sig1c, consumed before conv2)
  float* s2tot2 = t1;                                       // 262,144 (sig2a -> sig2b, after pw2)

  aug1_kernel<<<dim3(4, B_), 256, 0, stream>>>(x, a1_w0, a1_b0, a1_w1, a1_b1, a1_w2, a1_b2, h);
  wt_kernel<<<(SIGC1 * K_ * H1 + 255) / 256, 256, 0, stream>>>(a2_w0, w0t);
  sig1a_kernel<<<dim3(NCH, B_), 512, 0, stream>>>(h, s2tot1);
  sig1b_kernel<<<B_, 512, 0, stream>>>(h, s2tot1, s2pre1);
  sig1c_kernel<<<dim3(NCH, B_), 512, 0, stream>>>(h, s2pre1, s1);
  conv2_kernel<<<dim3(16, B_), 256, 0, stream>>>(s1, w0t, a2_b0, t1);
  pw2_kernel<<<dim3(4, B_), 256, 0, stream>>>(t1, a2_w1, a2_b1, a2_w2, a2_b2, h2);
  sig2a_kernel<<<dim3(NCH, B_), 256, 0, stream>>>(h2, lengths, s2tot2);
  sig2b_kernel<<<B_, 256, 0, stream>>>(h2, lengths, s2tot2, lin_w, lin_b, outp);
}

// Round 5
// 408.027 us; speedup vs baseline: 2.4589x; 1.2139x over previous
//
#include <hip/hip_runtime.h>
#include <hip/hip_bf16.h>

#define B_    64
#define S_    1024
#define CIN   5
#define K_    4
#define H1    64
#define H2    16
#define OUT_  32
#define L1_   1021      // S - K + 1
#define C1    22        // H2 + CIN + 1
#define C1SQ  484
#define SIGC1 506       // C1 + C1*C1
#define L2_   1018      // L1 - K + 1
#define SIGC2 272       // H2 + H2*H2
#define NCH   16        // time chunks (64 steps each)
#define RPAD  1032      // s1 row allocation (max staged row = 1031)
#define CPAD  512       // s1 channel pad

typedef __attribute__((ext_vector_type(8))) short short8;
typedef __attribute__((ext_vector_type(16))) float f32x16;

__device__ __forceinline__ unsigned short f2bf(float v) {
  __hip_bfloat16 h = __float2bfloat16(v);
  return *reinterpret_cast<unsigned short*>(&h);
}
__device__ __forceinline__ float bf2f(unsigned short u) {
  __hip_bfloat16 h;
  *reinterpret_cast<unsigned short*>(&h) = u;
  return __bfloat162float(h);
}

// ---------------- Kernel A: augment1 ----------
__global__ __launch_bounds__(256) void aug1_kernel(
    const float* __restrict__ x,
    const float* __restrict__ w0, const float* __restrict__ b0,
    const float* __restrict__ w1, const float* __restrict__ b1,
    const float* __restrict__ w2, const float* __restrict__ b2,
    float* __restrict__ h) {
  int b = blockIdx.y;
  int l = blockIdx.x * 256 + threadIdx.x;
  if (l >= L1_) return;
  const float* xb = x + (size_t)b * S_ * CIN;

  float t1[H1];
#pragma unroll
  for (int o = 0; o < H1; ++o) t1[o] = b0[o];
  for (int j = 0; j < K_; ++j) {
    for (int c = 0; c < CIN; ++c) {
      float xv = xb[(l + j) * CIN + c];
#pragma unroll
      for (int o = 0; o < H1; ++o) t1[o] += xv * w0[o * (CIN * K_) + c * K_ + j];
    }
  }
#pragma unroll
  for (int o = 0; o < H1; ++o) t1[o] = fmaxf(t1[o], 0.f);

  float t3[H2];
#pragma unroll
  for (int q = 0; q < H2; ++q) t3[q] = b2[q];
  for (int ch = 0; ch < 4; ++ch) {
    float t2c[16];
    for (int oc = 0; oc < 16; ++oc) {
      int o = ch * 16 + oc;
      float a = b1[o];
#pragma unroll
      for (int i = 0; i < H1; ++i) a += t1[i] * w1[o * H1 + i];
      t2c[oc] = fmaxf(a, 0.f);
    }
#pragma unroll
    for (int q = 0; q < H2; ++q) {
      float a = t3[q];
#pragma unroll
      for (int oc = 0; oc < 16; ++oc) a += t2c[oc] * w2[q * H1 + ch * 16 + oc];
      t3[q] = a;
    }
  }

  float* hr = h + ((size_t)b * L1_ + l) * C1;
#pragma unroll
  for (int c = 0; c < CIN; ++c) hr[c] = xb[(l + K_ - 1) * CIN + c];
  hr[CIN] = (float)l / (float)(L1_ - 1);
#pragma unroll
  for (int q = 0; q < H2; ++q) hr[CIN + 1 + q] = t3[q];
}

// ---------------- sig1 phase A: per-(b,chunk) local depth-2 scan, chunk totals only -----------------
__global__ __launch_bounds__(512) void sig1a_kernel(const float* __restrict__ h, float* __restrict__ s2tot) {
  int k = blockIdx.x, b = blockIdx.y;
  int tid = threadIdx.x;
  int start = k * 64, end = min(start + 63, L1_ - 1);
  const float* hb = h + (size_t)b * L1_ * C1;
  __shared__ float curb[2][C1];
  __shared__ float hpre[C1];
  if (tid < C1) {
    float v = (k == 0) ? 0.f : hb[(start - 1) * C1 + tid];
    hpre[tid] = v;
    curb[1][tid] = 0.f;
  }
  int i = tid / C1, j = tid - i * C1;
  float s2 = 0.f;
  int par = 0;
  __syncthreads();
  for (int t = start; t <= end; ++t) {
    if (tid < C1) curb[par][tid] = hb[t * C1 + tid] - hpre[tid];
    __syncthreads();
    if (tid < C1SQ) {
      float cj = curb[par][j], pj = curb[par ^ 1][j];
      float ci = curb[par][i], pi = curb[par ^ 1][i];
      float dj = cj - pj;
      s2 += pi * dj + 0.5f * (ci - pi) * dj;
    }
    __syncthreads();
    par ^= 1;
  }
  if (tid < C1SQ) s2tot[((size_t)b * NCH + k) * C1SQ + tid] = s2;
}

// ---------------- sig1 phase B: 16-step exclusive prefix combine via Chen -----------------
__global__ __launch_bounds__(512) void sig1b_kernel(const float* __restrict__ h, const float* __restrict__ s2tot,
                                                    float* __restrict__ s2pre) {
  int b = blockIdx.x;
  int tid = threadIdx.x;
  const float* hb = h + (size_t)b * L1_ * C1;
  __shared__ float bv[NCH + 1][C1];
  if (tid < (NCH + 1) * C1) {
    int kk = tid / C1, c = tid - kk * C1;
    float v = 0.f;
    if (kk > 0) {
      int row = (kk == NCH) ? (L1_ - 1) : (64 * kk - 1);
      v = hb[row * C1 + c];
    }
    bv[kk][c] = v;
  }
  int i = tid / C1, j = tid - i * C1;
  __syncthreads();
  if (tid >= C1SQ) return;
  float s2p = 0.f;
  for (int k = 0; k < NCH; ++k) {
    size_t idx = ((size_t)b * NCH + k) * C1SQ + tid;
    s2pre[idx] = s2p;
    s2p += bv[k][i] * (bv[k + 1][j] - bv[k][j]) + s2tot[idx];
  }
}

// ---------------- sig1 phase C: re-scan, emit global stream signature as swizzled bf16 hi/lo planes ----
// Element (t, c) stored at u16 index: t*512 + (c>>6)*64 + (((c>>3)&7) ^ (t&7))*8 + (c&7)
__global__ __launch_bounds__(512) void sig1c_kernel(const float* __restrict__ h, const float* __restrict__ s2pre,
                                                    unsigned short* __restrict__ s1hi,
                                                    unsigned short* __restrict__ s1lo) {
  int k = blockIdx.x, b = blockIdx.y;
  int tid = threadIdx.x;
  int start = k * 64, end = min(start + 63, L1_ - 1);
  const float* hb = h + (size_t)b * L1_ * C1;
  unsigned short* hio = s1hi + (size_t)b * RPAD * CPAD;
  unsigned short* loo = s1lo + (size_t)b * RPAD * CPAD;
  __shared__ float curb[2][C1];
  __shared__ float hpre[C1];
  if (tid < C1) {
    float v = (k == 0) ? 0.f : hb[(start - 1) * C1 + tid];
    hpre[tid] = v;
    curb[1][tid] = 0.f;
  }
  int i = tid / C1, j = tid - i * C1;
  // output channel this thread owns
  int c = (tid < C1SQ) ? (C1 + tid) : ((tid < C1SQ + C1) ? (tid - C1SQ) : tid);
  int cbase = (c >> 6) * 64 + (c & 7);
  int cg = (c >> 3) & 7;
  float s2 = 0.f;
  int par = 0;
  __syncthreads();
  float s2p = 0.f, hpi = 0.f;
  if (tid < C1SQ) {
    s2p = s2pre[((size_t)b * NCH + k) * C1SQ + tid];
    hpi = hpre[i];
  }
  for (int t = start; t <= end; ++t) {
    if (tid < C1) curb[par][tid] = hb[t * C1 + tid] - hpre[tid];
    __syncthreads();
    float v;
    if (tid < C1SQ) {
      float cj = curb[par][j], pj = curb[par ^ 1][j];
      float ci = curb[par][i], pi = curb[par ^ 1][i];
      float dj = cj - pj;
      s2 += pi * dj + 0.5f * (ci - pi) * dj;
      v = s2p + hpi * cj + s2;                 // Chen: A2 + A1 (x) B1 + B2
    } else if (tid < C1SQ + C1) {
      v = curb[par][c] + hpre[c];              // level 1 = unshifted h[t]
    } else {
      v = 0.f;                                 // pad channels 506..511
    }
    unsigned short hb16 = f2bf(v);
    unsigned short lb16 = f2bf(v - bf2f(hb16));
    size_t off = (size_t)t * CPAD + cbase + ((size_t)(cg ^ (t & 7)) << 3);
    hio[off] = hb16;
    loo[off] = lb16;
    __syncthreads();
    par ^= 1;
  }
}

// ---------------- Kernel W2: pack a2_w0 into B-fragment order, bf16 hi/lo ---------------------------
// Per-plane elem index: ((ot*128 + ksg)*64 + lane)*8 + e ; ksg = j*32 + cc*4 + ks
// maps to weight w0[o][(c,j)] with o = ot*32 + (lane&31), c = cc*64 + ks*16 + (lane>>5)*8 + e
__global__ __launch_bounds__(256) void wt2_kernel(const float* __restrict__ w0,
                                                  unsigned short* __restrict__ bhi,
                                                  unsigned short* __restrict__ blo) {
  int idx = blockIdx.x * 256 + threadIdx.x;
  if (idx >= 2 * 128 * 64 * 8) return;
  int e = idx & 7;
  int lane = (idx >> 3) & 63;
  int ksg = (idx >> 9) & 127;
  int ot = idx >> 16;
  int j = ksg >> 5, cc = (ksg >> 2) & 7, ks = ksg & 3;
  int o = ot * 32 + (lane & 31);
  int c = cc * 64 + ks * 16 + (lane >> 5) * 8 + e;
  float v = (c < SIGC1) ? w0[o * (SIGC1 * K_) + c * K_ + j] : 0.f;
  unsigned short hb16 = f2bf(v);
  bhi[idx] = hb16;
  blo[idx] = f2bf(v - bf2f(hb16));
}

// ---------------- Kernel C: MFMA conv (3-pass bf16 hi/lo) + fused pointwise convs -> h2 -------------
// Block: 128 l-rows x 64 o. 4 waves; wave w: wm=w>>1 (row half), wo=w&1 (o half); 2 acc tiles/wave.
__global__ __launch_bounds__(256) void conv2pw_kernel(
    const unsigned short* __restrict__ s1hi, const unsigned short* __restrict__ s1lo,
    const unsigned short* __restrict__ bpkhi, const unsigned short* __restrict__ bpklo,
    const float* __restrict__ b0,
    const float* __restrict__ w1, const float* __restrict__ b1,
    const float* __restrict__ w2, const float* __restrict__ b2,
    float* __restrict__ h2) {
  __shared__ char smem[69632];  // A: hi[2][136][128], lo[2][136][128] ; epilogue reuses
  int tid = threadIdx.x;
  int lane = tid & 63, w = tid >> 6;
  int wm = w >> 1, wo = w & 1;
  int b = blockIdx.y, l0 = blockIdx.x * 128;
  const char* ghi = (const char*)(s1hi + (size_t)b * RPAD * CPAD) + (size_t)l0 * 1024;
  const char* glo = (const char*)(s1lo + (size_t)b * RPAD * CPAD) + (size_t)l0 * 1024;
  f32x16 acc0 = {}, acc1 = {};
  int khalf = lane >> 5;
  int r0 = 64 * wm + (lane & 31);
  const unsigned short* bh0 = bpkhi + (size_t)wo * 65536 + lane * 8;
  const unsigned short* bl0 = bpklo + (size_t)wo * 65536 + lane * 8;

  int buf = 0;
  // prologue stage chunk 0
  {
    int srcoff = 0 * 128 + (lane & 7) * 16;
    for (int li = w; li < 17; li += 4) {
      int rowoff = (li * 8 + (lane >> 3)) * 1024;
      __builtin_amdgcn_global_load_lds(
          (const __attribute__((address_space(1))) void*)(ghi + rowoff + srcoff),
          (__attribute__((address_space(3))) void*)(smem + li * 1024), 16, 0, 0);
      __builtin_amdgcn_global_load_lds(
          (const __attribute__((address_space(1))) void*)(glo + rowoff + srcoff),
          (__attribute__((address_space(3))) void*)(smem + 34816 + li * 1024), 16, 0, 0);
    }
  }
  for (int cc = 0; cc < 8; ++cc) {
    __syncthreads();  // staged chunk `buf` visible (compiler drains vmcnt)
    if (cc < 7) {
      int srcoff = (cc + 1) * 128 + (lane & 7) * 16;
      int bo = (buf ^ 1) * 17408;
      for (int li = w; li < 17; li += 4) {
        int rowoff = (li * 8 + (lane >> 3)) * 1024;
        __builtin_amdgcn_global_load_lds(
            (const __attribute__((address_space(1))) void*)(ghi + rowoff + srcoff),
            (__attribute__((address_space(3))) void*)(smem + bo + li * 1024), 16, 0, 0);
        __builtin_amdgcn_global_load_lds(
            (const __attribute__((address_space(1))) void*)(glo + rowoff + srcoff),
            (__attribute__((address_space(3))) void*)(smem + 34816 + bo + li * 1024), 16, 0, 0);
      }
    }
    const char* Ah = smem + buf * 17408;
    const char* Al = smem + 34816 + buf * 17408;
#pragma unroll
    for (int j = 0; j < 4; ++j) {
      int ra = r0 + j, rb = ra + 32;
      const char* ah0 = Ah + ra * 128;
      const char* al0 = Al + ra * 128;
      const char* ah1 = Ah + rb * 128;
      const char* al1 = Al + rb * 128;
      int rxa = ra & 7, rxb = rb & 7;
#pragma unroll
      for (int ks = 0; ks < 4; ++ks) {
        int ksg = j * 32 + cc * 4 + ks;
        int gsel = ks * 2 + khalf;
        int ga = (gsel ^ rxa) << 4, gb = (gsel ^ rxb) << 4;
        short8 a0h = *(const short8*)(ah0 + ga);
        short8 a0l = *(const short8*)(al0 + ga);
        short8 a1h = *(const short8*)(ah1 + gb);
        short8 a1l = *(const short8*)(al1 + gb);
        short8 bhf = *(const short8*)(bh0 + ksg * 512);
        short8 blf = *(const short8*)(bl0 + ksg * 512);
        acc0 = __builtin_amdgcn_mfma_f32_32x32x16_bf16(a0h, bhf, acc0, 0, 0, 0);
        acc0 = __builtin_amdgcn_mfma_f32_32x32x16_bf16(a0h, blf, acc0, 0, 0, 0);
        acc0 = __builtin_amdgcn_mfma_f32_32x32x16_bf16(a0l, bhf, acc0, 0, 0, 0);
        acc1 = __builtin_amdgcn_mfma_f32_32x32x16_bf16(a1h, bhf, acc1, 0, 0, 0);
        acc1 = __builtin_amdgcn_mfma_f32_32x32x16_bf16(a1h, blf, acc1, 0, 0, 0);
        acc1 = __builtin_amdgcn_mfma_f32_32x32x16_bf16(a1l, bhf, acc1, 0, 0, 0);
      }
    }
    buf ^= 1;
  }
  __syncthreads();
  // ---- epilogue: relu(t1+b0) tile -> LDS [128][65] ----
  float* t1s = (float*)smem;                 // 33,280 B
  float* parts = (float*)(smem + 33280);     // [128][2][16] = 16,384 B
  {
    int col = 32 * wo + (lane & 31);
    float bb = b0[col];
    int rbase = 64 * wm + 4 * (lane >> 5);
#pragma unroll
    for (int rg = 0; rg < 16; ++rg) {
      int row = (rg & 3) + 8 * (rg >> 2) + rbase;
      t1s[row * 65 + col] = fmaxf(acc0[rg] + bb, 0.f);
      t1s[(row + 32) * 65 + col] = fmaxf(acc1[rg] + bb, 0.f);
    }
  }
  __syncthreads();
  // ---- fused pw: relu already applied; 1x1(64->64) relu, 1x1(64->16) ----
  {
    int prow = tid >> 1, qh = tid & 1;
    const float* trow = t1s + prow * 65;
    float mid[32];
#pragma unroll
    for (int oc = 0; oc < 32; ++oc) {
      int o = qh * 32 + oc;
      float a = b1[o];
      for (int i2 = 0; i2 < 64; ++i2) a += trow[i2] * w1[o * 64 + i2];
      mid[oc] = fmaxf(a, 0.f);
    }
#pragma unroll
    for (int p = 0; p < 16; ++p) {
      float a = 0.f;
#pragma unroll
      for (int oc = 0; oc < 32; ++oc) a += mid[oc] * w2[p * 64 + qh * 32 + oc];
      parts[(prow * 2 + qh) * 16 + p] = a;
    }
  }
  __syncthreads();
  {
    int row = tid >> 1, p0 = (tid & 1) * 8;
    int l = l0 + row;
    if (l < L2_) {
      float* outr = h2 + ((size_t)b * L2_ + l) * H2;
#pragma unroll
      for (int e = 0; e < 8; ++e) {
        int p = p0 + e;
        outr[p] = b2[p] + parts[row * 32 + p] + parts[row * 32 + 16 + p];
      }
    }
  }
}

// ---------------- sig2 phase A: per-(b,chunk) local scan with become_constant clamp -----------------
__global__ __launch_bounds__(256) void sig2a_kernel(const float* __restrict__ h2, const int* __restrict__ lengths,
                                                    float* __restrict__ s2tot2) {
  int k = blockIdx.x, b = blockIdx.y;
  int tid = threadIdx.x;
  int i = tid >> 4, j = tid & 15;
  int adjm1 = lengths[b] - (2 * K_ - 2) - 1;  // lengths - 7
  int start = k * 64, end = min(start + 63, L2_ - 1);
  size_t oidx = ((size_t)b * NCH + k) * 256 + tid;
  if (k > 0 && start - 1 >= adjm1) {
    s2tot2[oidx] = 0.f;
    return;
  }
  const float* h2b = h2 + (size_t)b * L2_ * H2;
  __shared__ float curb[2][H2];
  __shared__ float pre[H2];
  if (tid < H2) {
    float v = 0.f;
    if (k > 0) {
      int row = min(start - 1, adjm1);
      v = h2b[row * H2 + tid];
    }
    pre[tid] = v;
    curb[1][tid] = 0.f;
  }
  float s2 = 0.f;
  int par = 0;
  __syncthreads();
  for (int t = start; t <= end; ++t) {
    int row = min(t, adjm1);
    if (tid < H2) curb[par][tid] = h2b[row * H2 + tid] - pre[tid];
    __syncthreads();
    {
      float cj = curb[par][j], pj = curb[par ^ 1][j];
      float ci = curb[par][i], pi = curb[par ^ 1][i];
      float dj = cj - pj;
      s2 += pi * dj + 0.5f * (ci - pi) * dj;
    }
    __syncthreads();
    par ^= 1;
  }
  s2tot2[oidx] = s2;
}

// ---------------- sig2 phase B: 16-step Chen combine + final linear -----------------
__global__ __launch_bounds__(256) void sig2b_kernel(const float* __restrict__ h2, const int* __restrict__ lengths,
                                                    const float* __restrict__ s2tot2,
                                                    const float* __restrict__ lin_w, const float* __restrict__ lin_b,
                                                    float* __restrict__ out) {
  int b = blockIdx.x;
  int tid = threadIdx.x;
  int i = tid >> 4, j = tid & 15;
  int adjm1 = lengths[b] - (2 * K_ - 2) - 1;
  const float* h2b = h2 + (size_t)b * L2_ * H2;
  __shared__ float bv[NCH + 1][H2];
  __shared__ float s2s[SIGC2];
  for (int idx = tid; idx < (NCH + 1) * H2; idx += 256) {
    int kk = idx >> 4, c = idx & 15;
    float v = 0.f;
    if (kk > 0) {
      int row = min(64 * kk - 1, adjm1);
      v = h2b[row * H2 + c];
    }
    bv[kk][c] = v;
  }
  __syncthreads();
  float s2 = 0.f;
  for (int k = 0; k < NCH; ++k) {
    s2 += bv[k][i] * (bv[k + 1][j] - bv[k][j]) + s2tot2[((size_t)b * NCH + k) * 256 + tid];
  }
  s2s[H2 + tid] = s2;
  if (tid < H2) s2s[tid] = bv[NCH][tid];
  __syncthreads();
  if (tid < OUT_) {
    float a = lin_b[tid];
    for (int c = 0; c < SIGC2; ++c) a += s2s[c] * lin_w[tid * SIGC2 + c];
    out[b * OUT_ + tid] = a;
  }
}

extern "C" void kernel_launch(void* const* d_in, const int* in_sizes, int n_in,
                              void* d_out, int out_size, void* d_ws, size_t ws_size,
                              hipStream_t stream) {
  const float* x      = (const float*)d_in[0];
  const int*   lengths= (const int*)d_in[1];
  const float* a1_w0  = (const float*)d_in[2];
  const float* a1_b0  = (const float*)d_in[3];
  const float* a1_w1  = (const float*)d_in[4];
  const float* a1_b1  = (const float*)d_in[5];
  const float* a1_w2  = (const float*)d_in[6];
  const float* a1_b2  = (const float*)d_in[7];
  const float* a2_w0  = (const float*)d_in[8];
  const float* a2_b0  = (const float*)d_in[9];
  const float* a2_w1  = (const float*)d_in[10];
  const float* a2_b1  = (const float*)d_in[11];
  const float* a2_w2  = (const float*)d_in[12];
  const float* a2_b2  = (const float*)d_in[13];
  const float* lin_w  = (const float*)d_in[14];
  const float* lin_b  = (const float*)d_in[15];
  float* outp = (float*)d_out;

  float* ws = (float*)d_ws;
  // layout (float offsets):
  float* h = ws;                                            // 1,437,568
  unsigned short* s1hi = (unsigned short*)(ws + 1437568);   // 33,816,576 u16 (16,908,288 f)
  unsigned short* s1lo = s1hi + (size_t)B_ * RPAD * CPAD;   // same size
  unsigned short* bpkhi = (unsigned short*)(ws + 35254144); // 131,072 u16 (65,536 f)
  unsigned short* bpklo = bpkhi + 131072;
  float* h2 = ws + 35385216;                                // 1,042,432 -> total 36,427,648 f (145.7 MB)
  // aliases: sig1 scratch lives in (not-yet-written) h2 region; sig2 scratch in dead s1 region
  float* s2tot1 = h2;                                       // 495,616
  float* s2pre1 = h2 + 495616;                              // 495,616
  float* s2tot2 = (float*)s1hi;                             // 262,144 (s1 dead after conv2pw)

  aug1_kernel<<<dim3(4, B_), 256, 0, stream>>>(x, a1_w0, a1_b0, a1_w1, a1_b1, a1_w2, a1_b2, h);
  wt2_kernel<<<(2 * 128 * 64 * 8 + 255) / 256, 256, 0, stream>>>(a2_w0, bpkhi, bpklo);
  sig1a_kernel<<<dim3(NCH, B_), 512, 0, stream>>>(h, s2tot1);
  sig1b_kernel<<<B_, 512, 0, stream>>>(h, s2tot1, s2pre1);
  sig1c_kernel<<<dim3(NCH, B_), 512, 0, stream>>>(h, s2pre1, s1hi, s1lo);
  conv2pw_kernel<<<dim3(8, B_), 256, 0, stream>>>(s1hi, s1lo, bpkhi, bpklo, a2_b0,
                                                  a2_w1, a2_b1, a2_w2, a2_b2, h2);
  sig2a_kernel<<<dim3(NCH, B_), 256, 0, stream>>>(h2, lengths, s2tot2);
  sig2b_kernel<<<B_, 256, 0, stream>>>(h2, lengths, s2tot2, lin_w, lin_b, outp);
}